// Round 2
// 2168.851 us; speedup vs baseline: 1.2420x; 1.2420x over previous
//
#include <hip/hip_runtime.h>

#define BATCH 512
#define SEQ   128
#define EMBED 300
#define UNITS 512

typedef short  short8   __attribute__((ext_vector_type(8)));
typedef int    intx4    __attribute__((ext_vector_type(4)));
typedef float  floatx16 __attribute__((ext_vector_type(16)));

#define KXF 19     // x K-frags (304 = 19*16)
#define KHF 32     // h K-frags (512 = 32*16)
#define NGRP 4     // row groups (128 rows each)
#define ROWS 128   // batch rows per group
#define XROW 608   // bytes per packed bf16 x-row (304*2)

// ---- LDS: ALL weights + token mask. b0 in LDS (not VGPR) so the 51
// in-flight asm-load destinations can never be spill-copied (a spill of a
// pending load dest stores garbage). 120832B -> 1 WG/CU -> 4 waves on 4
// SIMDs -> 512-VGPR budget/wave, no spills. ----
#define SH_B0   0                    // rec B cf0: 32kf * 64 lanes * 16B
#define SH_B1   32768                // rec B cf1
#define SH_B2   65536                // x  B frags: 2cf * 19kf * 1024B = 38912
#define SH_MASK 104448               // token!=0 bytes: 128 rows * 128 t
#define SMEM_BYTES 120832

// ---- ws layout (total 1,675,264 B = the already-granted footprint) ----
#define WS_FLAGS 0                   // 4 groups * 32 WGs * 16B = 2048
#define WS_HBUF  4096                // 2 * 512 rows * 1024B (bf16 row-major)
#define WS_XBUF  (4096 + 1048576)    // 2 * 4 * 77824
#define XBUF_SZ  (ROWS * XROW)       // 77824
#define WS_NEED  (WS_XBUF + 2 * NGRP * XBUF_SZ)

__device__ __forceinline__ unsigned short f2bf(float f) {
  union { float f; unsigned u; } v; v.f = f;
  unsigned r = v.u + 0x7fff + ((v.u >> 16) & 1);
  return (unsigned short)(r >> 16);
}
__device__ __forceinline__ float sigm(float x) { return 1.f / (1.f + __expf(-x)); }
__device__ __forceinline__ float tanh_f(float x) {
  float e = __expf(2.f * x);
  return 1.f - 2.f / (e + 1.f);
}

// agent-scope (MALL-coherent) exchange store — identical to the proven R0 path
__device__ __forceinline__ void g_store32(unsigned* p, unsigned v) {
  __hip_atomic_store(p, v, __ATOMIC_RELAXED, __HIP_MEMORY_SCOPE_AGENT);
}

// exchange load, 16B: issued WITHOUT a wait; caller batches issues and waits
// with counted VWAIT(N). sc0+sc1 = bypass L1 and L2, read at the MALL
// (coherence point for cross-XCD exchange). volatile asm keeps program order
// among issues, so vmcnt retire order == issue order.
__device__ __forceinline__ short8 ldx16(const char* p) {
  intx4 v;
  asm volatile("global_load_dwordx4 %0, %1, off sc0 sc1" : "=v"(v) : "v"(p));
  return __builtin_bit_cast(short8, v);
}

// counted wait + sched_barrier: pins consuming MFMAs below the wait
// (ERRATA #18). Extra compiler VMEM between issue and wait only makes the
// wait stricter (vmcnt retires in order) — never an under-wait.
#define VWAIT(N) do { asm volatile("s_waitcnt vmcnt(" #N ")" ::: "memory"); \
                      __builtin_amdgcn_sched_barrier(0); } while (0)

// R0-proven group barrier poll: 32 flags, 16B stride, one load-round/poll
__device__ __forceinline__ void poll_ge(const unsigned* gf, int lane, unsigned tgt) {
  const unsigned* p = gf + (lane & 31) * 4;
  for (;;) {
    unsigned v = __hip_atomic_load(p, __ATOMIC_RELAXED, __HIP_MEMORY_SCOPE_AGENT);
    if (__ballot(v >= tgt) == ~0ull) break;
    __builtin_amdgcn_s_sleep(1);
  }
}

#define MFMA_(a, b, c) __builtin_amdgcn_mfma_f32_32x32x16_bf16(a, b, c, 0, 0, 0)

#define ISSUE_H(arr, base)                                                  \
  do { _Pragma("unroll")                                                    \
    for (int j = 0; j < 8; ++j) arr[j] = ldx16(hrow + ((base) + j) * 32);   \
  } while (0)

#define MFMA_H_GRP(arr, base)                                               \
  do { _Pragma("unroll")                                                    \
    for (int j = 0; j < 8; ++j) {                                           \
      const int kf = (base) + j;                                            \
      short8 p0 = *(const short8*)(sh_b0 + (kf * 64 + lane) * 16);          \
      short8 p1 = *(const short8*)(sh_b1 + (kf * 64 + lane) * 16);          \
      acc0 = MFMA_(arr[j], p0, acc0);                                       \
      acc1 = MFMA_(arr[j], p1, acc1);                                       \
    }                                                                       \
  } while (0)

extern "C" __global__ void __launch_bounds__(256, 1)
lstm_enc(const int* __restrict__ seq, const float* __restrict__ h0,
         const float* __restrict__ c0, const float* __restrict__ emb,
         const float* __restrict__ kern, const float* __restrict__ rkern,
         const float* __restrict__ bias, float* __restrict__ out,
         char* __restrict__ ws)
{
  extern __shared__ __align__(16) char smem[];
  char* sh_b0 = smem + SH_B0;
  char* sh_b1 = smem + SH_B1;
  char* sh_b2 = smem + SH_B2;
  char* sh_mk = smem + SH_MASK;

  const int tid  = threadIdx.x;
  const int lane = tid & 63;
  const int w    = tid >> 6;          // wave 0..3: rows w*32..w*32+31 of group
  const int rb   = blockIdx.x & 3;    // row group (128 rows)
  const int ug   = blockIdx.x >> 2;   // unit block 0..31

  unsigned* gflags = (unsigned*)(ws + WS_FLAGS) + rb * 128;  // 32 flags *16B
  unsigned* myflag = gflags + ug * 4;
  char* const hb0 = ws + WS_HBUF;
  char* const hb1 = ws + WS_HBUF + 524288;
  char* const xb0 = ws + WS_XBUF + rb * XBUF_SZ;
  char* const xb1 = ws + WS_XBUF + (NGRP + rb) * XBUF_SZ;

  const int  n    = lane & 31;
  const int  half = lane >> 5;
  const int  u    = ug * 16 + (n & 15);
  const bool lo   = (n < 16);

  const int gcol0 = (lo ? 0    : 512 ) + (n & 15) + ug * 16;  // [i|f]
  const int gcol1 = (lo ? 1024 : 1536) + (n & 15) + ug * 16;  // [g|o]

  // ---- rec_kernel B-frags -> LDS (waves split the kf range) ----
  for (int kf = w; kf < KHF; kf += 4) {
    int k0 = kf * 16 + half * 8;
    short8 p0, p1;
#pragma unroll
    for (int j = 0; j < 8; ++j) {
      p0[j] = (short)f2bf(rkern[(k0 + j) * 2048 + gcol0]);
      p1[j] = (short)f2bf(rkern[(k0 + j) * 2048 + gcol1]);
    }
    *(short8*)(sh_b0 + (kf * 64 + lane) * 16) = p0;
    *(short8*)(sh_b1 + (kf * 64 + lane) * 16) = p1;
  }
  // ---- x-weight B-frags -> LDS ----
  for (int kf = w; kf < KXF; kf += 4) {
    int k0 = kf * 16 + half * 8;
    short8 p0, p1;
#pragma unroll
    for (int j = 0; j < 8; ++j) {
      int k = k0 + j;
      p0[j] = (short)((k < EMBED) ? f2bf(kern[k * 2048 + gcol0]) : 0);
      p1[j] = (short)((k < EMBED) ? f2bf(kern[k * 2048 + gcol1]) : 0);
    }
    *(short8*)(sh_b2 + ((0 * KXF + kf) * 64 + lane) * 16) = p0;
    *(short8*)(sh_b2 + ((1 * KXF + kf) * 64 + lane) * 16) = p1;
  }
  // ---- token mask -> LDS bytes (seq slice for this group is linear) ----
  for (int i = tid; i < ROWS * SEQ; i += 256) {
    int tok = seq[rb * (ROWS * SEQ) + i];
    sh_mk[i] = (char)(tok != 0);
  }

  const float bsi = bias[u], bsf = bias[512 + u], bsg = bias[1024 + u], bso = bias[1536 + u];

  // ---- init h/c; publish h(0) bf16 row-major into hb1 ----
  float hreg[16], creg[16];
#pragma unroll
  for (int r = 0; r < 16; ++r) {
    int rowl = (r & 3) + 8 * (r >> 2) + 4 * half;
    int brow = rb * ROWS + w * 32 + rowl;
    float hv = h0[brow * 512 + u];
    float cv = c0[brow * 512 + u];
    hreg[r] = hv; creg[r] = cv;
    float hp = __shfl_xor(hv, 1, 64);
    if (lo && !(n & 1)) {
      unsigned d = (unsigned)f2bf(hv) | ((unsigned)f2bf(hp) << 16);
      g_store32((unsigned*)(hb1 + brow * 1024 + u * 2), d);
    }
  }

  // ---- gather x(0) into xb0 (WG owns group-local rows 4*ug..4*ug+3) ----
  {
    const int r0 = rb * ROWS + 4 * ug;
#pragma unroll
    for (int r = 0; r < 4; ++r) {
      const int tok = seq[(r0 + r) * SEQ + 0];
      const float* erow = emb + (long)tok * EMBED;
      char* xd = xb0 + (4 * ug + r) * XROW;
      if (tid < 152) {
        const int k = 2 * tid;
        float a  = (k     < EMBED) ? erow[k]     : 0.f;
        float b2 = (k + 1 < EMBED) ? erow[k + 1] : 0.f;
        g_store32((unsigned*)(xd + tid * 4),
                  (unsigned)f2bf(a) | ((unsigned)f2bf(b2) << 16));
      }
    }
  }

  __syncthreads();                    // drains vmcnt (per wave) before flag
  if (tid == 0) g_store32(myflag, 1u);

#pragma unroll 1
  for (int t = 0; t < SEQ; ++t) {
    const char* hsrc = (t & 1) ? hb0 : hb1;   // h(t)
    char*       hdst = (t & 1) ? hb1 : hb0;   // h(t+1)
    const char* xsrc = (t & 1) ? xb1 : xb0;   // x(t)
    char*       xdst = (t & 1) ? xb0 : xb1;   // x(t+1)

    // ---- prefetch x(t+1) gather into regs BEFORE the poll (read-only
    //      data; its latency hides under the barrier wait) ----
    unsigned gx[4] = {0u, 0u, 0u, 0u};
    if (t < SEQ - 1) {
      const int r0 = rb * ROWS + 4 * ug;
#pragma unroll
      for (int r = 0; r < 4; ++r) {
        const int tok = seq[(r0 + r) * SEQ + (t + 1)];
        const float* erow = emb + (long)tok * EMBED;
        if (tid < 152) {
          const int k = 2 * tid;
          float a  = (k     < EMBED) ? erow[k]     : 0.f;
          float b2 = (k + 1 < EMBED) ? erow[k + 1] : 0.f;
          gx[r] = (unsigned)f2bf(a) | ((unsigned)f2bf(b2) << 16);
        }
      }
    }

    // ---- barrier: x(t), h(t) visible. Poll drains vmcnt to 0, so the
    //      counted waits below see exactly our 51 exchange loads. ----
    poll_ge(gflags, lane, (unsigned)(t + 1));

    const char* xrow = xsrc + (w * 32 + n) * XROW + half * 16;
    const char* hrow = hsrc + (rb * ROWS + w * 32 + n) * 1024 + half * 16;

    // ---- batched issue: 19 x-frags + all 32 h-frags (51 in flight) ----
    short8 xf[KXF];
#pragma unroll
    for (int kf = 0; kf < KXF; ++kf) xf[kf] = ldx16(xrow + kf * 32);
    short8 hA[8], hB[8], hC[8], hD[8];
    ISSUE_H(hA, 0);
    ISSUE_H(hB, 8);
    ISSUE_H(hC, 16);
    ISSUE_H(hD, 24);

    floatx16 acc0, acc1;
#pragma unroll
    for (int i = 0; i < 16; ++i) { acc0[i] = 0.f; acc1[i] = 0.f; }

    VWAIT(32);                 // 19 oldest (xf) complete; h frags still fly
#pragma unroll
    for (int kf = 0; kf < KXF; ++kf) {
      short8 p0 = *(const short8*)(sh_b2 + ((0 * KXF + kf) * 64 + lane) * 16);
      short8 p1 = *(const short8*)(sh_b2 + ((1 * KXF + kf) * 64 + lane) * 16);
      acc0 = MFMA_(xf[kf], p0, acc0);
      acc1 = MFMA_(xf[kf], p1, acc1);
    }
    VWAIT(24);  MFMA_H_GRP(hA, 0);    // h windows drain under x/h MFMA work
    VWAIT(16);  MFMA_H_GRP(hB, 8);
    VWAIT(8);   MFMA_H_GRP(hC, 16);
    VWAIT(0);   MFMA_H_GRP(hD, 24);

    // ---- epilogue: gates, state, mask, publish h(t+1) ----
#pragma unroll
    for (int r = 0; r < 16; ++r) {
      float a0 = acc0[r], a1 = acc1[r];
      float s0 = __shfl_xor(a0, 16, 64);
      float s1 = __shfl_xor(a1, 16, 64);
      float zi = (lo ? a0 : s0) + bsi;
      float zf = (lo ? s0 : a0) + bsf;
      float zg = (lo ? a1 : s1) + bsg;
      float zo = (lo ? s1 : a1) + bso;
      float iv = sigm(zi), fv = sigm(zf), gv = tanh_f(zg), ov = sigm(zo);
      float cn = fv * creg[r] + iv * gv;
      float hn = ov * tanh_f(cn);
      int rowl = (r & 3) + 8 * (r >> 2) + 4 * half;
      int lrow = w * 32 + rowl;
      int brow = rb * ROWS + lrow;
      if (sh_mk[lrow * SEQ + t] == 0) { cn = creg[r]; hn = hreg[r]; }
      creg[r] = cn; hreg[r] = hn;
      float hp = __shfl_xor(hn, 1, 64);
      if (lo) {
        out[brow * (SEQ * 512) + t * 512 + u] = hn;
        if (!(n & 1)) {
          unsigned d = (unsigned)f2bf(hn) | ((unsigned)f2bf(hp) << 16);
          g_store32((unsigned*)(hdst + brow * 1024 + u * 2), d);
        }
        if (t == SEQ - 1) {
          out[BATCH * SEQ * 512 + brow * 512 + u] = hn;
          out[BATCH * SEQ * 512 + BATCH * 512 + brow * 512 + u] = cn;
        }
      }
    }

    // ---- write x(t+1) from regs; arrive ----
    if (t < SEQ - 1) {
      const int r0 = 4 * ug;
#pragma unroll
      for (int r = 0; r < 4; ++r) {
        if (tid < 152)
          g_store32((unsigned*)(xdst + (r0 + r) * XROW + tid * 4), gx[r]);
      }
      __syncthreads();                 // per-wave vmcnt(0) drain before flag
      if (tid == 0) g_store32(myflag, (unsigned)(t + 2));
    }
  }
}

extern "C" void kernel_launch(void* const* d_in, const int* in_sizes, int n_in,
                              void* d_out, int out_size, void* d_ws, size_t ws_size,
                              hipStream_t stream) {
  if (ws_size < (size_t)WS_NEED) return;
  const int*   seq   = (const int*)d_in[0];
  const float* h0    = (const float*)d_in[1];
  const float* c0    = (const float*)d_in[2];
  const float* emb   = (const float*)d_in[3];
  const float* kern  = (const float*)d_in[4];
  const float* rkern = (const float*)d_in[5];
  const float* bias  = (const float*)d_in[6];
  float* out = (float*)d_out;

  hipFuncSetAttribute((const void*)lstm_enc,
                      hipFuncAttributeMaxDynamicSharedMemorySize, SMEM_BYTES);
  hipMemsetAsync(d_ws, 0, 4096, stream);  // zero barrier flags
  lstm_enc<<<dim3(128), dim3(256), SMEM_BYTES, stream>>>(
      seq, h0, c0, emb, kern, rkern, bias, out, (char*)d_ws);
}